// Round 3
// baseline (107.798 us; speedup 1.0000x reference)
//
#include <hip/hip_runtime.h>
#include <hip/hip_bf16.h>

// LocallyConnected1d: x (64,64,1024) f32, weights (1024,64,64,9) f32, bias (64,1024) f32
// out[b*65536 + w*64 + o] = sum_{c,k} x[b,c,w+k-4] * weights[w,o,c,k] + bias_flat[w*64+o]
// Per-w GEMM: M=64 (b), N=64 (o), K=576 (c*9+t). Weight stream (151MB, read-once) is
// the roofline; structure = copy-kernel-like rolling prefetch + single-barrier block.

typedef __bf16 bf16x8 __attribute__((ext_vector_type(8)));
typedef float  f32x4  __attribute__((ext_vector_type(4)));
typedef float  f32x4u __attribute__((ext_vector_type(4), aligned(4)));

#define NK   576
#define LDK  584   // 576 + 8 pad: row stride 1168B = 73*16 (odd*16) -> conflict-free-ish b128 reads
#define NCH  18    // K chunks of 32
#define PFD  6     // rolling prefetch depth (chunks)

__global__ __launch_bounds__(256, 2)
void lc1d_mfma_kernel(const float* __restrict__ x,
                      const float* __restrict__ wts,
                      const float* __restrict__ bias,
                      float* __restrict__ out) {
    __shared__ __bf16 Alds[64][LDK];

    const int w    = blockIdx.x;
    const int tid  = threadIdx.x;
    const int lane = tid & 63;
    const int wv   = tid >> 6;          // wave -> o strip
    const int m16  = lane & 15;
    const int ko   = (lane >> 4) * 8;   // k slice within 32-chunk
    const int o    = wv * 16 + m16;

    const float* wbase = wts + (size_t)w * (64 * NK) + (size_t)o * NK + ko;

    // ---------- stage A panel: Alds[b][c*9+t] = bf16(x[b][c][w-4+t]), t=0..8 ----------
    if (w >= 4 && w <= 1015) {
        // FAST path: window fully interior -> unaligned vector loads, static scatter.
        // Phase A: 2 lanes per (b,c) row load f32x4 at taps 4h..4h+3
        {
            const int rsel = tid >> 1;      // 0..127
            const int h    = tid & 1;
            const int pb   = w - 4 + h * 4;
            #pragma unroll 4
            for (int i = 0; i < 32; ++i) {
                int R = i * 128 + rsel;     // row = b*64+c, 0..4095
                int c = R & 63, b = R >> 6;
                f32x4 v = *reinterpret_cast<const f32x4u*>(x + (size_t)R * 1024 + pb);
                __bf16* dst = &Alds[b][c * 9 + h * 4];
                dst[0] = (__bf16)v[0];
                dst[1] = (__bf16)v[1];
                dst[2] = (__bf16)v[2];
                dst[3] = (__bf16)v[3];
            }
        }
        // Phase B: tap 8, one scalar per row
        {
            #pragma unroll 4
            for (int i = 0; i < 16; ++i) {
                int R = i * 256 + tid;
                int c = R & 63, b = R >> 6;
                float v = x[(size_t)R * 1024 + (w + 4)];
                Alds[b][c * 9 + 8] = (__bf16)v;
            }
        }
    } else {
        // EDGE path (16 blocks): aligned loads, predicated scatter (round-2 proven).
        const int rsel = tid >> 2;          // 0..63
        const int sl   = tid & 3;
        const int a0   = (w - 4) & ~3;
        const int d    = (w - 4) - a0;      // 0..3
        const int p0   = a0 + sl * 4;
        const bool inb = ((unsigned)p0 < 1024u);   // whole-vector valid (4-aligned)
        #pragma unroll 4
        for (int i = 0; i < 64; ++i) {
            int R = i * 64 + rsel;
            int c = R & 63, b = R >> 6;
            f32x4 v = (f32x4){0.f, 0.f, 0.f, 0.f};
            if (inb) v = *reinterpret_cast<const f32x4*>(x + (size_t)R * 1024 + p0);
            __bf16* dst = &Alds[b][c * 9];
            #pragma unroll
            for (int j = 0; j < 4; ++j) {
                int t = sl * 4 + j - d;
                if (t >= 0 && t <= 8) dst[t] = (__bf16)v[j];
            }
        }
    }
    __syncthreads();   // the only barrier

    // ---------- weight stream + MFMA, rolling prefetch ----------
    f32x4 acc[4];
    #pragma unroll
    for (int i = 0; i < 4; ++i) acc[i] = (f32x4){0.f, 0.f, 0.f, 0.f};

    f32x4 wr0[PFD], wr1[PFD];
    #pragma unroll
    for (int p = 0; p < PFD; ++p) {
        wr0[p] = *reinterpret_cast<const f32x4*>(wbase + p * 32);
        wr1[p] = *reinterpret_cast<const f32x4*>(wbase + p * 32 + 4);
    }

    #pragma unroll
    for (int it = 0; it < NCH; ++it) {
        const int s = it % PFD;             // static after full unroll
        f32x4 u0 = wr0[s], u1 = wr1[s];
        if (it + PFD < NCH) {
            wr0[s] = *reinterpret_cast<const f32x4*>(wbase + (it + PFD) * 32);
            wr1[s] = *reinterpret_cast<const f32x4*>(wbase + (it + PFD) * 32 + 4);
        }
        bf16x8 bf;
        #pragma unroll
        for (int j = 0; j < 4; ++j) { bf[j] = (__bf16)u0[j]; bf[j + 4] = (__bf16)u1[j]; }
        const int kk0 = it * 32;
        #pragma unroll
        for (int bt = 0; bt < 4; ++bt) {
            bf16x8 af = *reinterpret_cast<const bf16x8*>(&Alds[bt * 16 + m16][kk0 + ko]);
            acc[bt] = __builtin_amdgcn_mfma_f32_16x16x32_bf16(af, bf, acc[bt], 0, 0, 0);
        }
    }

    // ---------- epilogue ----------
    const float bv = bias[w * 64 + o];
    const int r0 = (lane >> 4) * 4;
    float* outp = out + (size_t)w * 64 + o;
    #pragma unroll
    for (int bt = 0; bt < 4; ++bt) {
        #pragma unroll
        for (int r = 0; r < 4; ++r) {
            int b = bt * 16 + r0 + r;
            outp[(size_t)b * 65536] = acc[bt][r] + bv;
        }
    }
}

extern "C" void kernel_launch(void* const* d_in, const int* in_sizes, int n_in,
                              void* d_out, int out_size, void* d_ws, size_t ws_size,
                              hipStream_t stream) {
    const float* x    = (const float*)d_in[0];
    const float* wts  = (const float*)d_in[1];
    const float* bias = (const float*)d_in[2];
    float* out = (float*)d_out;
    lc1d_mfma_kernel<<<dim3(1024), dim3(256), 0, stream>>>(x, wts, bias, out);
}

// Round 4
// 63.034 us; speedup vs baseline: 1.7102x; 1.7102x over previous
//
#include <hip/hip_runtime.h>
#include <hip/hip_bf16.h>

// LocallyConnected1d: x (64,64,1024) f32, weights (1024,64,64,9) f32, bias (64,1024) f32
// out[b*65536 + w*64 + o] = sum_{c,t} x[b,c,w+t-4] * weights[w,o,c,t] + bias_flat[w*64+o]
// Two-kernel plan: (1) transpose+convert x -> Xt[pos+4][b][c] bf16 (8.45MB, L2/L3-hot,
// zero-padded edges); (2) per-w GEMM: weights streamed contiguously (151MB = roofline),
// A-panel staged from Xt with contiguous 16B loads + cheap LDS scatter. 2-phase, 4 blk/CU.

typedef __bf16 bf16x8 __attribute__((ext_vector_type(8)));
typedef float  f32x4  __attribute__((ext_vector_type(4)));

#define NK    576
#define PHK   288
#define LDAP  296                      // 288 + 8 pad
#define NITER 9
#define PFD   6
#define XT_SLABS 1032                  // pos -4 .. 1027 (stored at pos+4)
#define XT_BYTES ((size_t)XT_SLABS * 4096 * 2)   // 8,454,144 B

// ---------------- pre-pass: Xt[p+4][b][c] = bf16(x[b][c][p]) ----------------
__global__ __launch_bounds__(256)
void xt_transpose_kernel(const float* __restrict__ x, __bf16* __restrict__ xt) {
    __shared__ float T[64][17];        // 64 c x 16 pos (+1 pad)
    const int b      = blockIdx.x >> 2;
    const int p_base = (blockIdx.x & 3) * 256;
    const int tid  = threadIdx.x;
    const int cr   = tid >> 2;         // load: row c
    const int pq   = (tid & 3) * 4;    // load: pos offset within tile
    const int pl   = tid >> 3;         // write: pos 0..15 (tid<128)
    const int cg   = tid & 7;          // write: c-group 0..7

    for (int tile = 0; tile < 16; ++tile) {
        const int p0 = p_base + tile * 16;
        f32x4 v = *reinterpret_cast<const f32x4*>(x + (((size_t)(b * 64 + cr)) << 10) + p0 + pq);
        if (tile) __syncthreads();     // WAR on T
        T[cr][pq + 0] = v[0];
        T[cr][pq + 1] = v[1];
        T[cr][pq + 2] = v[2];
        T[cr][pq + 3] = v[3];
        __syncthreads();
        if (tid < 128) {
            bf16x8 o8;
            #pragma unroll
            for (int i = 0; i < 8; ++i) o8[i] = (__bf16)T[cg * 8 + i][pl];
            *reinterpret_cast<bf16x8*>(xt + (size_t)(p0 + pl + 4) * 4096 + b * 64 + cg * 8) = o8;
        }
    }
}

// ---------------- main kernel ----------------
__global__ __launch_bounds__(256, 4)
void lc1d_main_kernel(const __bf16* __restrict__ xt,
                      const float* __restrict__ wts,
                      const float* __restrict__ bias,
                      float* __restrict__ out) {
    __shared__ __bf16 Alds[64][LDAP];

    const int w    = blockIdx.x;
    const int tid  = threadIdx.x;
    const int lane = tid & 63;
    const int wv   = tid >> 6;
    const int m16  = lane & 15;
    const int ko   = (lane >> 4) * 8;
    const int o    = wv * 16 + m16;

    const float* wbase = wts + (size_t)w * (64 * NK) + (size_t)o * NK + ko;

    // staging: thread -> (b = tid>>2, c8 = (tid&3)*8), 9 taps, 8 bf16 each
    const int sb  = tid >> 2;
    const int sc8 = (tid & 3) * 8;

    f32x4 acc[4];
    #pragma unroll
    for (int i = 0; i < 4; ++i) acc[i] = (f32x4){0.f, 0.f, 0.f, 0.f};

    #pragma unroll
    for (int ph = 0; ph < 2; ++ph) {
        if (ph) __syncthreads();       // WAR: waves done reading previous phase

        // stage: Alds[sb][(sc8+i)*9+t] = Xt[w+t][sb][ph*32 + sc8 + i]
        #pragma unroll
        for (int t = 0; t < 9; ++t) {
            bf16x8 v = *reinterpret_cast<const bf16x8*>(
                xt + (size_t)(w + t) * 4096 + sb * 64 + ph * 32 + sc8);
            __bf16* dst = &Alds[sb][sc8 * 9 + t];
            #pragma unroll
            for (int i = 0; i < 8; ++i) dst[i * 9] = v[i];
        }
        __syncthreads();

        // weight stream + MFMA (rolling prefetch)
        const float* wp = wbase + ph * PHK;
        f32x4 wr0[PFD], wr1[PFD];
        #pragma unroll
        for (int p = 0; p < PFD; ++p) {
            wr0[p] = *reinterpret_cast<const f32x4*>(wp + p * 32);
            wr1[p] = *reinterpret_cast<const f32x4*>(wp + p * 32 + 4);
        }
        #pragma unroll
        for (int it = 0; it < NITER; ++it) {
            const int s = it % PFD;
            f32x4 u0 = wr0[s], u1 = wr1[s];
            if (it + PFD < NITER) {
                wr0[s] = *reinterpret_cast<const f32x4*>(wp + (it + PFD) * 32);
                wr1[s] = *reinterpret_cast<const f32x4*>(wp + (it + PFD) * 32 + 4);
            }
            bf16x8 bf;
            #pragma unroll
            for (int j = 0; j < 4; ++j) { bf[j] = (__bf16)u0[j]; bf[j + 4] = (__bf16)u1[j]; }
            const int kk0 = it * 32;
            #pragma unroll
            for (int bt = 0; bt < 4; ++bt) {
                bf16x8 af = *reinterpret_cast<const bf16x8*>(&Alds[bt * 16 + m16][kk0 + ko]);
                acc[bt] = __builtin_amdgcn_mfma_f32_16x16x32_bf16(af, bf, acc[bt], 0, 0, 0);
            }
        }
    }

    const float bv = bias[w * 64 + o];
    const int r0 = (lane >> 4) * 4;
    float* outp = out + (size_t)w * 64 + o;
    #pragma unroll
    for (int bt = 0; bt < 4; ++bt) {
        #pragma unroll
        for (int r = 0; r < 4; ++r) {
            int b = bt * 16 + r0 + r;
            outp[(size_t)b * 65536] = acc[bt][r] + bv;
        }
    }
}

// ---------------- fallback (round-2 proven, used if ws too small) ----------------
__global__ __launch_bounds__(256, 4)
void lc1d_fallback_kernel(const float* __restrict__ x,
                          const float* __restrict__ wts,
                          const float* __restrict__ bias,
                          float* __restrict__ out) {
    __shared__ __bf16 Alds[64][LDAP];
    const int w    = blockIdx.x;
    const int tid  = threadIdx.x;
    const int lane = tid & 63;
    const int wv   = tid >> 6;
    const int m16  = lane & 15;
    const int ko   = (lane >> 4) * 8;
    const int o    = wv * 16 + m16;
    const float* wbase = wts + (size_t)w * (64 * NK) + (size_t)o * NK + ko;
    const int xbase  = w - 4;
    const int a0     = xbase & ~3;
    const int d      = xbase - a0;
    const int rowsel = tid >> 2;
    const int sl     = tid & 3;
    const int p0     = a0 + sl * 4;
    const bool inb   = ((unsigned)p0 < 1024u);

    f32x4 acc[4];
    #pragma unroll
    for (int i = 0; i < 4; ++i) acc[i] = (f32x4){0.f, 0.f, 0.f, 0.f};

    #pragma unroll
    for (int ph = 0; ph < 2; ++ph) {
        f32x4 wr[2 * NITER];
        const float* wp = wbase + ph * PHK;
        #pragma unroll
        for (int it = 0; it < NITER; ++it) {
            wr[2 * it]     = *reinterpret_cast<const f32x4*>(wp + it * 32);
            wr[2 * it + 1] = *reinterpret_cast<const f32x4*>(wp + it * 32 + 4);
        }
        if (ph) __syncthreads();
        #pragma unroll 4
        for (int i = 0; i < 32; ++i) {
            int R  = i * 64 + rowsel;
            int c  = R & 31;
            int b  = R >> 5;
            int cc = ph * 32 + c;
            f32x4 v = (f32x4){0.f, 0.f, 0.f, 0.f};
            if (inb) v = *reinterpret_cast<const f32x4*>(x + (((size_t)(b * 64 + cc)) << 10) + p0);
            __bf16* dst = &Alds[b][c * 9];
            #pragma unroll
            for (int j = 0; j < 4; ++j) {
                int t = sl * 4 + j - d;
                if (t >= 0 && t <= 8) dst[t] = (__bf16)v[j];
            }
        }
        __syncthreads();
        #pragma unroll
        for (int it = 0; it < NITER; ++it) {
            bf16x8 bf;
            #pragma unroll
            for (int j = 0; j < 4; ++j) { bf[j] = (__bf16)wr[2 * it][j]; bf[j + 4] = (__bf16)wr[2 * it + 1][j]; }
            const int kk0 = it * 32;
            #pragma unroll
            for (int bt = 0; bt < 4; ++bt) {
                bf16x8 af = *reinterpret_cast<const bf16x8*>(&Alds[bt * 16 + m16][kk0 + ko]);
                acc[bt] = __builtin_amdgcn_mfma_f32_16x16x32_bf16(af, bf, acc[bt], 0, 0, 0);
            }
        }
    }
    const float bv = bias[w * 64 + o];
    const int r0 = (lane >> 4) * 4;
    float* outp = out + (size_t)w * 64 + o;
    #pragma unroll
    for (int bt = 0; bt < 4; ++bt) {
        #pragma unroll
        for (int r = 0; r < 4; ++r) {
            int b = bt * 16 + r0 + r;
            outp[(size_t)b * 65536] = acc[bt][r] + bv;
        }
    }
}

extern "C" void kernel_launch(void* const* d_in, const int* in_sizes, int n_in,
                              void* d_out, int out_size, void* d_ws, size_t ws_size,
                              hipStream_t stream) {
    const float* x    = (const float*)d_in[0];
    const float* wts  = (const float*)d_in[1];
    const float* bias = (const float*)d_in[2];
    float* out = (float*)d_out;

    if (ws_size >= XT_BYTES) {
        __bf16* xt = (__bf16*)d_ws;
        // zero the pad slabs (pos -4..-1 and 1024..1027)
        hipMemsetAsync(xt, 0, (size_t)4 * 4096 * 2, stream);
        hipMemsetAsync((char*)xt + (size_t)1028 * 4096 * 2, 0, (size_t)4 * 4096 * 2, stream);
        xt_transpose_kernel<<<dim3(256), dim3(256), 0, stream>>>(x, xt);
        lc1d_main_kernel<<<dim3(1024), dim3(256), 0, stream>>>(xt, wts, bias, out);
    } else {
        lc1d_fallback_kernel<<<dim3(1024), dim3(256), 0, stream>>>(x, wts, bias, out);
    }
}

// Round 5
// 57.233 us; speedup vs baseline: 1.8835x; 1.1014x over previous
//
#include <hip/hip_runtime.h>
#include <hip/hip_bf16.h>

// LocallyConnected1d: x (64,64,1024) f32, weights (1024,64,64,9) f32, bias (64,1024) f32
// out[b*65536 + w*64 + o] = sum_{c,t} x[b,c,w+t-4] * weights[w,o,c,t] + bias_flat[w*64+o]
// Plan: prepass transposes x -> Xt[pos+4][b][c] bf16 (8.45MB, L2-hot, zero-padded, pads
// zeroed by 8 extra prepass blocks). Main kernel: per-w GEMM M=64,N=64,K=576; weight
// stream (151MB read-once) is the roofline -> continuous 18-chunk rolling prefetch that
// survives barriers (lgkmcnt-only barrier), A staged via reg-transpose + ds_write_b128.

typedef __bf16 bf16x8 __attribute__((ext_vector_type(8)));
typedef float  f32x4  __attribute__((ext_vector_type(4)));

#define NK    576
#define LDAP  296                      // 288 + 8 pad (per-phase panel)
#define NCH   18
#define PFD   6
#define XT_SLABS 1032                  // pos -4 .. 1027 stored at pos+4
#define XT_BYTES ((size_t)XT_SLABS * 4096 * 2)

// barrier that does NOT drain vmcnt (keeps weight prefetch in flight)
#define LGKM_BAR() asm volatile("s_waitcnt lgkmcnt(0)\n\ts_barrier" ::: "memory")

// ---------------- pre-pass: Xt[p+4][b][c] = bf16(x[b][c][p]); blocks 256..263 zero pads ----
__global__ __launch_bounds__(256)
void xt_transpose_kernel(const float* __restrict__ x, __bf16* __restrict__ xt) {
    const int tid = threadIdx.x;
    if (blockIdx.x >= 256) {
        const int s    = blockIdx.x - 256;               // 0..7
        const int slab = (s < 4) ? s : (1024 + s);       // 0..3, 1028..1031
        f32x4* p = reinterpret_cast<f32x4*>(xt + (size_t)slab * 4096);
        const f32x4 z = (f32x4){0.f, 0.f, 0.f, 0.f};
        p[tid] = z;          // 256*16B
        p[256 + tid] = z;    // remaining 4096B of the 8KB slab
        return;
    }
    __shared__ float T[64][17];
    const int b      = blockIdx.x >> 2;
    const int p_base = (blockIdx.x & 3) * 256;
    const int cr = tid >> 2;
    const int pq = (tid & 3) * 4;
    const int pl = tid >> 3;
    const int cg = tid & 7;

    for (int tile = 0; tile < 16; ++tile) {
        const int p0 = p_base + tile * 16;
        f32x4 v = *reinterpret_cast<const f32x4*>(x + (((size_t)(b * 64 + cr)) << 10) + p0 + pq);
        if (tile) __syncthreads();
        T[cr][pq + 0] = v[0];
        T[cr][pq + 1] = v[1];
        T[cr][pq + 2] = v[2];
        T[cr][pq + 3] = v[3];
        __syncthreads();
        if (tid < 128) {
            bf16x8 o8;
            #pragma unroll
            for (int i = 0; i < 8; ++i) o8[i] = (__bf16)T[cg * 8 + i][pl];
            *reinterpret_cast<bf16x8*>(xt + (size_t)(p0 + pl + 4) * 4096 + b * 64 + cg * 8) = o8;
        }
    }
}

// ---------------- main kernel ----------------
__global__ __launch_bounds__(256, 4)
void lc1d_main_kernel(const __bf16* __restrict__ xt,
                      const float* __restrict__ wts,
                      const float* __restrict__ bias,
                      float* __restrict__ out) {
    __shared__ __bf16 Alds[64][LDAP];

    const int w    = blockIdx.x;
    const int tid  = threadIdx.x;
    const int lane = tid & 63;
    const int wv   = tid >> 6;
    const int m16  = lane & 15;
    const int ko   = (lane >> 4) * 8;
    const int o    = wv * 16 + m16;

    const float* wbase = wts + (size_t)w * (64 * NK) + (size_t)o * NK + ko;

    // staging geometry: thread -> (row sb, c-octet sc8); owns 72 consecutive k's (144B)
    const int sb  = tid >> 2;
    const int sc8 = (tid & 3) * 8;
    const __bf16* xtb = xt + (size_t)w * 4096 + sb * 64 + sc8;

    // ---- issue phase-0 Xt loads ----
    bf16x8 v[9];
    #pragma unroll
    for (int t = 0; t < 9; ++t)
        v[t] = *reinterpret_cast<const bf16x8*>(xtb + (size_t)t * 4096);

    // ---- start weight prefetch pipeline (chunks 0..PFD-1) ----
    f32x4 wr0[PFD], wr1[PFD];
    #pragma unroll
    for (int p = 0; p < PFD; ++p) {
        wr0[p] = *reinterpret_cast<const f32x4*>(wbase + p * 32);
        wr1[p] = *reinterpret_cast<const f32x4*>(wbase + p * 32 + 4);
    }

    // ---- transpose + write phase 0 (9 x ds_write_b128) ----
    {
        __bf16* dst = &Alds[sb][sc8 * 9];
        #pragma unroll
        for (int q = 0; q < 9; ++q) {
            bf16x8 u;
            #pragma unroll
            for (int j = 0; j < 8; ++j) { int n = q * 8 + j; u[j] = v[n % 9][n / 9]; }
            *reinterpret_cast<bf16x8*>(dst + q * 8) = u;
        }
    }
    LGKM_BAR();

    f32x4 acc[4];
    #pragma unroll
    for (int i = 0; i < 4; ++i) acc[i] = (f32x4){0.f, 0.f, 0.f, 0.f};

    // ---- issue phase-1 Xt loads (held in regs; written after WAR barrier) ----
    #pragma unroll
    for (int t = 0; t < 9; ++t)
        v[t] = *reinterpret_cast<const bf16x8*>(xtb + 32 + (size_t)t * 4096);

    // ---- phase 0 MFMA: chunks 0..8, rolling prefetch continues ----
    #pragma unroll
    for (int it = 0; it < 9; ++it) {
        const int s = it % PFD;
        f32x4 u0 = wr0[s], u1 = wr1[s];
        wr0[s] = *reinterpret_cast<const f32x4*>(wbase + (it + PFD) * 32);
        wr1[s] = *reinterpret_cast<const f32x4*>(wbase + (it + PFD) * 32 + 4);
        bf16x8 bf;
        #pragma unroll
        for (int j = 0; j < 4; ++j) { bf[j] = (__bf16)u0[j]; bf[j + 4] = (__bf16)u1[j]; }
        const int kk0 = it * 32;
        #pragma unroll
        for (int bt = 0; bt < 4; ++bt) {
            bf16x8 af = *reinterpret_cast<const bf16x8*>(&Alds[bt * 16 + m16][kk0 + ko]);
            acc[bt] = __builtin_amdgcn_mfma_f32_16x16x32_bf16(af, bf, acc[bt], 0, 0, 0);
        }
    }

    LGKM_BAR();   // WAR: all waves done reading phase-0 panel

    // ---- transpose + write phase 1 ----
    {
        __bf16* dst = &Alds[sb][sc8 * 9];
        #pragma unroll
        for (int q = 0; q < 9; ++q) {
            bf16x8 u;
            #pragma unroll
            for (int j = 0; j < 8; ++j) { int n = q * 8 + j; u[j] = v[n % 9][n / 9]; }
            *reinterpret_cast<bf16x8*>(dst + q * 8) = u;
        }
    }
    LGKM_BAR();

    // ---- phase 1 MFMA: chunks 9..17 ----
    #pragma unroll
    for (int it = 9; it < NCH; ++it) {
        const int s = it % PFD;
        f32x4 u0 = wr0[s], u1 = wr1[s];
        if (it + PFD < NCH) {
            wr0[s] = *reinterpret_cast<const f32x4*>(wbase + (it + PFD) * 32);
            wr1[s] = *reinterpret_cast<const f32x4*>(wbase + (it + PFD) * 32 + 4);
        }
        bf16x8 bf;
        #pragma unroll
        for (int j = 0; j < 4; ++j) { bf[j] = (__bf16)u0[j]; bf[j + 4] = (__bf16)u1[j]; }
        const int kk0 = (it - 9) * 32;
        #pragma unroll
        for (int bt = 0; bt < 4; ++bt) {
            bf16x8 af = *reinterpret_cast<const bf16x8*>(&Alds[bt * 16 + m16][kk0 + ko]);
            acc[bt] = __builtin_amdgcn_mfma_f32_16x16x32_bf16(af, bf, acc[bt], 0, 0, 0);
        }
    }

    // ---- epilogue ----
    const float bv = bias[w * 64 + o];
    const int r0 = (lane >> 4) * 4;
    float* outp = out + (size_t)w * 64 + o;
    #pragma unroll
    for (int bt = 0; bt < 4; ++bt) {
        #pragma unroll
        for (int r = 0; r < 4; ++r) {
            int b = bt * 16 + r0 + r;
            outp[(size_t)b * 65536] = acc[bt][r] + bv;
        }
    }
}

// ---------------- fallback (round-2 proven, used if ws too small) ----------------
__global__ __launch_bounds__(256, 4)
void lc1d_fallback_kernel(const float* __restrict__ x,
                          const float* __restrict__ wts,
                          const float* __restrict__ bias,
                          float* __restrict__ out) {
    __shared__ __bf16 Alds[64][LDAP];
    const int w    = blockIdx.x;
    const int tid  = threadIdx.x;
    const int lane = tid & 63;
    const int wv   = tid >> 6;
    const int m16  = lane & 15;
    const int ko   = (lane >> 4) * 8;
    const int o    = wv * 16 + m16;
    const float* wbase = wts + (size_t)w * (64 * NK) + (size_t)o * NK + ko;
    const int xbase  = w - 4;
    const int a0     = xbase & ~3;
    const int d      = xbase - a0;
    const int rowsel = tid >> 2;
    const int sl     = tid & 3;
    const int p0     = a0 + sl * 4;
    const bool inb   = ((unsigned)p0 < 1024u);

    f32x4 acc[4];
    #pragma unroll
    for (int i = 0; i < 4; ++i) acc[i] = (f32x4){0.f, 0.f, 0.f, 0.f};

    #pragma unroll
    for (int ph = 0; ph < 2; ++ph) {
        f32x4 wr[18];
        const float* wp = wbase + ph * 288;
        #pragma unroll
        for (int it = 0; it < 9; ++it) {
            wr[2 * it]     = *reinterpret_cast<const f32x4*>(wp + it * 32);
            wr[2 * it + 1] = *reinterpret_cast<const f32x4*>(wp + it * 32 + 4);
        }
        if (ph) __syncthreads();
        #pragma unroll 4
        for (int i = 0; i < 32; ++i) {
            int R  = i * 64 + rowsel;
            int c  = R & 31;
            int b  = R >> 5;
            int cc = ph * 32 + c;
            f32x4 vv = (f32x4){0.f, 0.f, 0.f, 0.f};
            if (inb) vv = *reinterpret_cast<const f32x4*>(x + (((size_t)(b * 64 + cc)) << 10) + p0);
            __bf16* dst = &Alds[b][c * 9];
            #pragma unroll
            for (int j = 0; j < 4; ++j) {
                int t = sl * 4 + j - d;
                if (t >= 0 && t <= 8) dst[t] = (__bf16)vv[j];
            }
        }
        __syncthreads();
        #pragma unroll
        for (int it = 0; it < 9; ++it) {
            bf16x8 bf;
            #pragma unroll
            for (int j = 0; j < 4; ++j) { bf[j] = (__bf16)wr[2 * it][j]; bf[j + 4] = (__bf16)wr[2 * it + 1][j]; }
            const int kk0 = it * 32;
            #pragma unroll
            for (int bt = 0; bt < 4; ++bt) {
                bf16x8 af = *reinterpret_cast<const bf16x8*>(&Alds[bt * 16 + m16][kk0 + ko]);
                acc[bt] = __builtin_amdgcn_mfma_f32_16x16x32_bf16(af, bf, acc[bt], 0, 0, 0);
            }
        }
    }
    const float bv = bias[w * 64 + o];
    const int r0 = (lane >> 4) * 4;
    float* outp = out + (size_t)w * 64 + o;
    #pragma unroll
    for (int bt = 0; bt < 4; ++bt) {
        #pragma unroll
        for (int r = 0; r < 4; ++r) {
            int b = bt * 16 + r0 + r;
            outp[(size_t)b * 65536] = acc[bt][r] + bv;
        }
    }
}

extern "C" void kernel_launch(void* const* d_in, const int* in_sizes, int n_in,
                              void* d_out, int out_size, void* d_ws, size_t ws_size,
                              hipStream_t stream) {
    const float* x    = (const float*)d_in[0];
    const float* wts  = (const float*)d_in[1];
    const float* bias = (const float*)d_in[2];
    float* out = (float*)d_out;

    if (ws_size >= XT_BYTES) {
        __bf16* xt = (__bf16*)d_ws;
        xt_transpose_kernel<<<dim3(264), dim3(256), 0, stream>>>(x, xt);
        lc1d_main_kernel<<<dim3(1024), dim3(256), 0, stream>>>(xt, wts, bias, out);
    } else {
        lc1d_fallback_kernel<<<dim3(1024), dim3(256), 0, stream>>>(x, wts, bias, out);
    }
}

// Round 6
// 43.435 us; speedup vs baseline: 2.4819x; 1.3177x over previous
//
#include <hip/hip_runtime.h>
#include <hip/hip_bf16.h>

// LocallyConnected1d: x (64,64,1024) f32, weights (1024,64,64,9) f32, bias (64,1024) f32
// out[b*65536 + w*64 + o] = sum_{c,t} x[b,c,w+t-4] * weights[w,o,c,t] + bias_flat[w*64+o]
// Prepass: x -> Xt[pos+4][b][c] bf16 (8.45MB, zero-padded). Main: per-w GEMM M=64,N=64,
// K=576; weight stream (151MB read-once) = roofline; rolling register prefetch survives
// lgkmcnt-only barriers; A staged via reg-transpose + ds_write_b128.
// Round 6: XCD-contiguous w mapping (w = (orig&7)*128 + orig>>3) so each XCD's Xt
// working set is ~1.1MB -> per-XCD-L2 resident (Xt slab reused by 9 neighboring w).

typedef __bf16 bf16x8 __attribute__((ext_vector_type(8)));
typedef float  f32x4  __attribute__((ext_vector_type(4)));

#define NK    576
#define LDAP  296                      // 288 + 8 pad (per-phase panel)
#define NCH   18
#define PFD   6
#define XT_SLABS 1032                  // pos -4 .. 1027 stored at pos+4
#define XT_BYTES ((size_t)XT_SLABS * 4096 * 2)

// barrier that does NOT drain vmcnt (keeps weight prefetch in flight)
#define LGKM_BAR() asm volatile("s_waitcnt lgkmcnt(0)\n\ts_barrier" ::: "memory")

// ---------------- pre-pass: Xt[p+4][b][c] = bf16(x[b][c][p]); blocks 256..263 zero pads ----
__global__ __launch_bounds__(256)
void xt_transpose_kernel(const float* __restrict__ x, __bf16* __restrict__ xt) {
    const int tid = threadIdx.x;
    if (blockIdx.x >= 256) {
        const int s    = blockIdx.x - 256;               // 0..7
        const int slab = (s < 4) ? s : (1024 + s);       // 0..3, 1028..1031
        f32x4* p = reinterpret_cast<f32x4*>(xt + (size_t)slab * 4096);
        const f32x4 z = (f32x4){0.f, 0.f, 0.f, 0.f};
        p[tid] = z;
        p[256 + tid] = z;
        return;
    }
    __shared__ float T[64][17];
    const int b      = blockIdx.x >> 2;
    const int p_base = (blockIdx.x & 3) * 256;
    const int cr = tid >> 2;
    const int pq = (tid & 3) * 4;
    const int pl = tid >> 3;
    const int cg = tid & 7;

    for (int tile = 0; tile < 16; ++tile) {
        const int p0 = p_base + tile * 16;
        f32x4 v = *reinterpret_cast<const f32x4*>(x + (((size_t)(b * 64 + cr)) << 10) + p0 + pq);
        if (tile) __syncthreads();
        T[cr][pq + 0] = v[0];
        T[cr][pq + 1] = v[1];
        T[cr][pq + 2] = v[2];
        T[cr][pq + 3] = v[3];
        __syncthreads();
        if (tid < 128) {
            bf16x8 o8;
            #pragma unroll
            for (int i = 0; i < 8; ++i) o8[i] = (__bf16)T[cg * 8 + i][pl];
            *reinterpret_cast<bf16x8*>(xt + (size_t)(p0 + pl + 4) * 4096 + b * 64 + cg * 8) = o8;
        }
    }
}

// ---------------- main kernel ----------------
__global__ __launch_bounds__(256, 4)
void lc1d_main_kernel(const __bf16* __restrict__ xt,
                      const float* __restrict__ wts,
                      const float* __restrict__ bias,
                      float* __restrict__ out) {
    __shared__ __bf16 Alds[64][LDAP];

    // XCD-contiguous w mapping: 1024 = 8 XCD * 128. Block orig runs on XCD orig%8;
    // give each XCD a contiguous w-range so Xt slabs (reused by 9 neighbor w) stay
    // in its 4MB L2.
    const int orig = blockIdx.x;
    const int w    = ((orig & 7) << 7) | (orig >> 3);

    const int tid  = threadIdx.x;
    const int lane = tid & 63;
    const int wv   = tid >> 6;
    const int m16  = lane & 15;
    const int ko   = (lane >> 4) * 8;
    const int o    = wv * 16 + m16;

    const float* wbase = wts + (size_t)w * (64 * NK) + (size_t)o * NK + ko;

    // staging geometry: thread -> (row sb, c-octet sc8); owns 72 consecutive k's (144B)
    const int sb  = tid >> 2;
    const int sc8 = (tid & 3) * 8;
    const __bf16* xtb = xt + (size_t)w * 4096 + sb * 64 + sc8;

    // ---- issue phase-0 Xt loads ----
    bf16x8 v[9];
    #pragma unroll
    for (int t = 0; t < 9; ++t)
        v[t] = *reinterpret_cast<const bf16x8*>(xtb + (size_t)t * 4096);

    // ---- start weight prefetch pipeline ----
    f32x4 wr0[PFD], wr1[PFD];
    #pragma unroll
    for (int p = 0; p < PFD; ++p) {
        wr0[p] = *reinterpret_cast<const f32x4*>(wbase + p * 32);
        wr1[p] = *reinterpret_cast<const f32x4*>(wbase + p * 32 + 4);
    }

    // ---- transpose + write phase 0 ----
    {
        __bf16* dst = &Alds[sb][sc8 * 9];
        #pragma unroll
        for (int q = 0; q < 9; ++q) {
            bf16x8 u;
            #pragma unroll
            for (int j = 0; j < 8; ++j) { int n = q * 8 + j; u[j] = v[n % 9][n / 9]; }
            *reinterpret_cast<bf16x8*>(dst + q * 8) = u;
        }
    }
    LGKM_BAR();

    f32x4 acc[4];
    #pragma unroll
    for (int i = 0; i < 4; ++i) acc[i] = (f32x4){0.f, 0.f, 0.f, 0.f};

    // ---- issue phase-1 Xt loads (written after WAR barrier) ----
    #pragma unroll
    for (int t = 0; t < 9; ++t)
        v[t] = *reinterpret_cast<const bf16x8*>(xtb + 32 + (size_t)t * 4096);

    // ---- phase 0 MFMA: chunks 0..8 ----
    #pragma unroll
    for (int it = 0; it < 9; ++it) {
        const int s = it % PFD;
        f32x4 u0 = wr0[s], u1 = wr1[s];
        wr0[s] = *reinterpret_cast<const f32x4*>(wbase + (it + PFD) * 32);
        wr1[s] = *reinterpret_cast<const f32x4*>(wbase + (it + PFD) * 32 + 4);
        bf16x8 bf;
        #pragma unroll
        for (int j = 0; j < 4; ++j) { bf[j] = (__bf16)u0[j]; bf[j + 4] = (__bf16)u1[j]; }
        const int kk0 = it * 32;
        #pragma unroll
        for (int bt = 0; bt < 4; ++bt) {
            bf16x8 af = *reinterpret_cast<const bf16x8*>(&Alds[bt * 16 + m16][kk0 + ko]);
            acc[bt] = __builtin_amdgcn_mfma_f32_16x16x32_bf16(af, bf, acc[bt], 0, 0, 0);
        }
    }

    LGKM_BAR();   // WAR: all waves done reading phase-0 panel

    // ---- transpose + write phase 1 ----
    {
        __bf16* dst = &Alds[sb][sc8 * 9];
        #pragma unroll
        for (int q = 0; q < 9; ++q) {
            bf16x8 u;
            #pragma unroll
            for (int j = 0; j < 8; ++j) { int n = q * 8 + j; u[j] = v[n % 9][n / 9]; }
            *reinterpret_cast<bf16x8*>(dst + q * 8) = u;
        }
    }
    LGKM_BAR();

    // ---- phase 1 MFMA: chunks 9..17 ----
    #pragma unroll
    for (int it = 9; it < NCH; ++it) {
        const int s = it % PFD;
        f32x4 u0 = wr0[s], u1 = wr1[s];
        if (it + PFD < NCH) {
            wr0[s] = *reinterpret_cast<const f32x4*>(wbase + (it + PFD) * 32);
            wr1[s] = *reinterpret_cast<const f32x4*>(wbase + (it + PFD) * 32 + 4);
        }
        bf16x8 bf;
        #pragma unroll
        for (int j = 0; j < 4; ++j) { bf[j] = (__bf16)u0[j]; bf[j + 4] = (__bf16)u1[j]; }
        const int kk0 = (it - 9) * 32;
        #pragma unroll
        for (int bt = 0; bt < 4; ++bt) {
            bf16x8 af = *reinterpret_cast<const bf16x8*>(&Alds[bt * 16 + m16][kk0 + ko]);
            acc[bt] = __builtin_amdgcn_mfma_f32_16x16x32_bf16(af, bf, acc[bt], 0, 0, 0);
        }
    }

    // ---- epilogue ----
    const float bv = bias[w * 64 + o];
    const int r0 = (lane >> 4) * 4;
    float* outp = out + (size_t)w * 64 + o;
    #pragma unroll
    for (int bt = 0; bt < 4; ++bt) {
        #pragma unroll
        for (int r = 0; r < 4; ++r) {
            int b = bt * 16 + r0 + r;
            outp[(size_t)b * 65536] = acc[bt][r] + bv;
        }
    }
}

// ---------------- fallback (round-2 proven, used if ws too small) ----------------
__global__ __launch_bounds__(256, 4)
void lc1d_fallback_kernel(const float* __restrict__ x,
                          const float* __restrict__ wts,
                          const float* __restrict__ bias,
                          float* __restrict__ out) {
    __shared__ __bf16 Alds[64][LDAP];
    const int w    = blockIdx.x;
    const int tid  = threadIdx.x;
    const int lane = tid & 63;
    const int wv   = tid >> 6;
    const int m16  = lane & 15;
    const int ko   = (lane >> 4) * 8;
    const int o    = wv * 16 + m16;
    const float* wbase = wts + (size_t)w * (64 * NK) + (size_t)o * NK + ko;
    const int xbase  = w - 4;
    const int a0     = xbase & ~3;
    const int d      = xbase - a0;
    const int rowsel = tid >> 2;
    const int sl     = tid & 3;
    const int p0     = a0 + sl * 4;
    const bool inb   = ((unsigned)p0 < 1024u);

    f32x4 acc[4];
    #pragma unroll
    for (int i = 0; i < 4; ++i) acc[i] = (f32x4){0.f, 0.f, 0.f, 0.f};

    #pragma unroll
    for (int ph = 0; ph < 2; ++ph) {
        f32x4 wr[18];
        const float* wp = wbase + ph * 288;
        #pragma unroll
        for (int it = 0; it < 9; ++it) {
            wr[2 * it]     = *reinterpret_cast<const f32x4*>(wp + it * 32);
            wr[2 * it + 1] = *reinterpret_cast<const f32x4*>(wp + it * 32 + 4);
        }
        if (ph) __syncthreads();
        #pragma unroll 4
        for (int i = 0; i < 32; ++i) {
            int R  = i * 64 + rowsel;
            int c  = R & 31;
            int b  = R >> 5;
            int cc = ph * 32 + c;
            f32x4 vv = (f32x4){0.f, 0.f, 0.f, 0.f};
            if (inb) vv = *reinterpret_cast<const f32x4*>(x + (((size_t)(b * 64 + cc)) << 10) + p0);
            __bf16* dst = &Alds[b][c * 9];
            #pragma unroll
            for (int j = 0; j < 4; ++j) {
                int t = sl * 4 + j - d;
                if (t >= 0 && t <= 8) dst[t] = (__bf16)vv[j];
            }
        }
        __syncthreads();
        #pragma unroll
        for (int it = 0; it < 9; ++it) {
            bf16x8 bf;
            #pragma unroll
            for (int j = 0; j < 4; ++j) { bf[j] = (__bf16)wr[2 * it][j]; bf[j + 4] = (__bf16)wr[2 * it + 1][j]; }
            const int kk0 = it * 32;
            #pragma unroll
            for (int bt = 0; bt < 4; ++bt) {
                bf16x8 af = *reinterpret_cast<const bf16x8*>(&Alds[bt * 16 + m16][kk0 + ko]);
                acc[bt] = __builtin_amdgcn_mfma_f32_16x16x32_bf16(af, bf, acc[bt], 0, 0, 0);
            }
        }
    }
    const float bv = bias[w * 64 + o];
    const int r0 = (lane >> 4) * 4;
    float* outp = out + (size_t)w * 64 + o;
    #pragma unroll
    for (int bt = 0; bt < 4; ++bt) {
        #pragma unroll
        for (int r = 0; r < 4; ++r) {
            int b = bt * 16 + r0 + r;
            outp[(size_t)b * 65536] = acc[bt][r] + bv;
        }
    }
}

extern "C" void kernel_launch(void* const* d_in, const int* in_sizes, int n_in,
                              void* d_out, int out_size, void* d_ws, size_t ws_size,
                              hipStream_t stream) {
    const float* x    = (const float*)d_in[0];
    const float* wts  = (const float*)d_in[1];
    const float* bias = (const float*)d_in[2];
    float* out = (float*)d_out;

    if (ws_size >= XT_BYTES) {
        __bf16* xt = (__bf16*)d_ws;
        xt_transpose_kernel<<<dim3(264), dim3(256), 0, stream>>>(x, xt);
        lc1d_main_kernel<<<dim3(1024), dim3(256), 0, stream>>>(xt, wts, bias, out);
    } else {
        lc1d_fallback_kernel<<<dim3(1024), dim3(256), 0, stream>>>(x, wts, bias, out);
    }
}

// Round 7
// 39.773 us; speedup vs baseline: 2.7103x; 1.0921x over previous
//
#include <hip/hip_runtime.h>
#include <hip/hip_bf16.h>

// LocallyConnected1d: x (64,64,1024) f32, weights (1024,64,64,9) f32, bias (64,1024) f32
// out[b*65536 + w*64 + o] = sum_{c,t} x[b,c,w+t-4] * weights[w,o,c,t] + bias_flat[w*64+o]
// Prepass: x -> Xt[pos+4][b][c] bf16 (8.45MB, zero-padded), one tile per block (no
// barrier chains). Main: per-w GEMM M=64,N=64,K=576; weight stream (151MB read-once)
// = roofline; rolling register prefetch survives lgkmcnt-only barriers; A staged via
// reg-transpose + ds_write_b128; XCD-contiguous w mapping keeps Xt per-XCD-L2-resident.

typedef __bf16 bf16x8 __attribute__((ext_vector_type(8)));
typedef float  f32x4  __attribute__((ext_vector_type(4)));

#define NK    576
#define LDAP  296                      // 288 + 8 pad (per-phase panel)
#define NCH   18
#define PFD   6
#define XT_SLABS 1032                  // pos -4 .. 1027 stored at pos+4
#define XT_BYTES ((size_t)XT_SLABS * 4096 * 2)

// barrier that does NOT drain vmcnt (keeps weight prefetch in flight)
#define LGKM_BAR() asm volatile("s_waitcnt lgkmcnt(0)\n\ts_barrier" ::: "memory")

// ---------------- pre-pass: Xt[p+4][b][c] = bf16(x[b][c][p]) ----------------
// One 32-pos tile per block: 2048 tile blocks + 8 pad-zero blocks. No loops, no
// barrier chains -> latency hidden by 8 blocks/CU TLP.
__global__ __launch_bounds__(256)
void xt_transpose_kernel(const float* __restrict__ x, __bf16* __restrict__ xt) {
    const int tid = threadIdx.x;
    if (blockIdx.x >= 2048) {
        const int s    = blockIdx.x - 2048;              // 0..7
        const int slab = (s < 4) ? s : (1024 + s);       // 0..3, 1028..1031
        f32x4* p = reinterpret_cast<f32x4*>(xt + (size_t)slab * 4096);
        const f32x4 z = (f32x4){0.f, 0.f, 0.f, 0.f};
        p[tid] = z;
        p[256 + tid] = z;
        return;
    }
    __shared__ float T[64][33];
    const int b  = blockIdx.x >> 5;          // 0..63
    const int p0 = (blockIdx.x & 31) * 32;   // 0,32,..,992

    // load: thread (c = tid>>2, q = tid&3) reads 32B = 2 x f32x4 of row c
    const int c = tid >> 2;
    const int q = tid & 3;
    const float* src = x + (((size_t)(b * 64 + c)) << 10) + p0 + q * 8;
    f32x4 v0 = *reinterpret_cast<const f32x4*>(src);
    f32x4 v1 = *reinterpret_cast<const f32x4*>(src + 4);
    #pragma unroll
    for (int i = 0; i < 4; ++i) { T[c][q * 8 + i] = v0[i]; T[c][q * 8 + 4 + i] = v1[i]; }
    __syncthreads();

    // write: thread (pl = tid>>3, cg = tid&7) emits bf16x8 of 8 c's at pos p0+pl
    const int pl = tid >> 3;                 // 0..31
    const int cg = tid & 7;                  // 0..7
    bf16x8 o8;
    #pragma unroll
    for (int i = 0; i < 8; ++i) o8[i] = (__bf16)T[cg * 8 + i][pl];
    *reinterpret_cast<bf16x8*>(xt + (size_t)(p0 + pl + 4) * 4096 + b * 64 + cg * 8) = o8;
}

// ---------------- main kernel ----------------
__global__ __launch_bounds__(256, 4)
void lc1d_main_kernel(const __bf16* __restrict__ xt,
                      const float* __restrict__ wts,
                      const float* __restrict__ bias,
                      float* __restrict__ out) {
    __shared__ __bf16 Alds[64][LDAP];

    // XCD-contiguous w mapping: 1024 = 8 XCD * 128; each XCD gets a contiguous
    // w-range so Xt slabs (reused by 9 neighbor w) stay in its 4MB L2.
    const int orig = blockIdx.x;
    const int w    = ((orig & 7) << 7) | (orig >> 3);

    const int tid  = threadIdx.x;
    const int lane = tid & 63;
    const int wv   = tid >> 6;
    const int m16  = lane & 15;
    const int ko   = (lane >> 4) * 8;
    const int o    = wv * 16 + m16;

    const float* wbase = wts + (size_t)w * (64 * NK) + (size_t)o * NK + ko;

    // hoisted epilogue bias load (latency hidden under the whole kernel)
    const float bv = bias[w * 64 + o];

    // staging geometry: thread -> (row sb, c-octet sc8); owns 72 consecutive k's (144B)
    const int sb  = tid >> 2;
    const int sc8 = (tid & 3) * 8;
    const __bf16* xtb = xt + (size_t)w * 4096 + sb * 64 + sc8;

    // ---- issue phase-0 Xt loads ----
    bf16x8 v[9];
    #pragma unroll
    for (int t = 0; t < 9; ++t)
        v[t] = *reinterpret_cast<const bf16x8*>(xtb + (size_t)t * 4096);

    // ---- start weight prefetch pipeline ----
    f32x4 wr0[PFD], wr1[PFD];
    #pragma unroll
    for (int p = 0; p < PFD; ++p) {
        wr0[p] = *reinterpret_cast<const f32x4*>(wbase + p * 32);
        wr1[p] = *reinterpret_cast<const f32x4*>(wbase + p * 32 + 4);
    }

    // ---- transpose + write phase 0 ----
    {
        __bf16* dst = &Alds[sb][sc8 * 9];
        #pragma unroll
        for (int qq = 0; qq < 9; ++qq) {
            bf16x8 u;
            #pragma unroll
            for (int j = 0; j < 8; ++j) { int n = qq * 8 + j; u[j] = v[n % 9][n / 9]; }
            *reinterpret_cast<bf16x8*>(dst + qq * 8) = u;
        }
    }
    LGKM_BAR();

    f32x4 acc[4];
    #pragma unroll
    for (int i = 0; i < 4; ++i) acc[i] = (f32x4){0.f, 0.f, 0.f, 0.f};

    // ---- issue phase-1 Xt loads (written after WAR barrier) ----
    #pragma unroll
    for (int t = 0; t < 9; ++t)
        v[t] = *reinterpret_cast<const bf16x8*>(xtb + 32 + (size_t)t * 4096);

    // ---- phase 0 MFMA: chunks 0..8 ----
    #pragma unroll
    for (int it = 0; it < 9; ++it) {
        const int s = it % PFD;
        f32x4 u0 = wr0[s], u1 = wr1[s];
        wr0[s] = *reinterpret_cast<const f32x4*>(wbase + (it + PFD) * 32);
        wr1[s] = *reinterpret_cast<const f32x4*>(wbase + (it + PFD) * 32 + 4);
        bf16x8 bf;
        #pragma unroll
        for (int j = 0; j < 4; ++j) { bf[j] = (__bf16)u0[j]; bf[j + 4] = (__bf16)u1[j]; }
        const int kk0 = it * 32;
        #pragma unroll
        for (int bt = 0; bt < 4; ++bt) {
            bf16x8 af = *reinterpret_cast<const bf16x8*>(&Alds[bt * 16 + m16][kk0 + ko]);
            acc[bt] = __builtin_amdgcn_mfma_f32_16x16x32_bf16(af, bf, acc[bt], 0, 0, 0);
        }
    }

    LGKM_BAR();   // WAR: all waves done reading phase-0 panel

    // ---- transpose + write phase 1 ----
    {
        __bf16* dst = &Alds[sb][sc8 * 9];
        #pragma unroll
        for (int qq = 0; qq < 9; ++qq) {
            bf16x8 u;
            #pragma unroll
            for (int j = 0; j < 8; ++j) { int n = qq * 8 + j; u[j] = v[n % 9][n / 9]; }
            *reinterpret_cast<bf16x8*>(dst + qq * 8) = u;
        }
    }
    LGKM_BAR();

    // ---- phase 1 MFMA: chunks 9..17 ----
    #pragma unroll
    for (int it = 9; it < NCH; ++it) {
        const int s = it % PFD;
        f32x4 u0 = wr0[s], u1 = wr1[s];
        if (it + PFD < NCH) {
            wr0[s] = *reinterpret_cast<const f32x4*>(wbase + (it + PFD) * 32);
            wr1[s] = *reinterpret_cast<const f32x4*>(wbase + (it + PFD) * 32 + 4);
        }
        bf16x8 bf;
        #pragma unroll
        for (int j = 0; j < 4; ++j) { bf[j] = (__bf16)u0[j]; bf[j + 4] = (__bf16)u1[j]; }
        const int kk0 = (it - 9) * 32;
        #pragma unroll
        for (int bt = 0; bt < 4; ++bt) {
            bf16x8 af = *reinterpret_cast<const bf16x8*>(&Alds[bt * 16 + m16][kk0 + ko]);
            acc[bt] = __builtin_amdgcn_mfma_f32_16x16x32_bf16(af, bf, acc[bt], 0, 0, 0);
        }
    }

    // ---- epilogue ----
    const int r0 = (lane >> 4) * 4;
    float* outp = out + (size_t)w * 64 + o;
    #pragma unroll
    for (int bt = 0; bt < 4; ++bt) {
        #pragma unroll
        for (int r = 0; r < 4; ++r) {
            int b = bt * 16 + r0 + r;
            outp[(size_t)b * 65536] = acc[bt][r] + bv;
        }
    }
}

// ---------------- fallback (round-2 proven, used if ws too small) ----------------
__global__ __launch_bounds__(256, 4)
void lc1d_fallback_kernel(const float* __restrict__ x,
                          const float* __restrict__ wts,
                          const float* __restrict__ bias,
                          float* __restrict__ out) {
    __shared__ __bf16 Alds[64][LDAP];
    const int w    = blockIdx.x;
    const int tid  = threadIdx.x;
    const int lane = tid & 63;
    const int wv   = tid >> 6;
    const int m16  = lane & 15;
    const int ko   = (lane >> 4) * 8;
    const int o    = wv * 16 + m16;
    const float* wbase = wts + (size_t)w * (64 * NK) + (size_t)o * NK + ko;
    const int xbase  = w - 4;
    const int a0     = xbase & ~3;
    const int d      = xbase - a0;
    const int rowsel = tid >> 2;
    const int sl     = tid & 3;
    const int p0     = a0 + sl * 4;
    const bool inb   = ((unsigned)p0 < 1024u);

    f32x4 acc[4];
    #pragma unroll
    for (int i = 0; i < 4; ++i) acc[i] = (f32x4){0.f, 0.f, 0.f, 0.f};

    #pragma unroll
    for (int ph = 0; ph < 2; ++ph) {
        f32x4 wr[18];
        const float* wp = wbase + ph * 288;
        #pragma unroll
        for (int it = 0; it < 9; ++it) {
            wr[2 * it]     = *reinterpret_cast<const f32x4*>(wp + it * 32);
            wr[2 * it + 1] = *reinterpret_cast<const f32x4*>(wp + it * 32 + 4);
        }
        if (ph) __syncthreads();
        #pragma unroll 4
        for (int i = 0; i < 32; ++i) {
            int R  = i * 64 + rowsel;
            int c  = R & 31;
            int b  = R >> 5;
            int cc = ph * 32 + c;
            f32x4 vv = (f32x4){0.f, 0.f, 0.f, 0.f};
            if (inb) vv = *reinterpret_cast<const f32x4*>(x + (((size_t)(b * 64 + cc)) << 10) + p0);
            __bf16* dst = &Alds[b][c * 9];
            #pragma unroll
            for (int j = 0; j < 4; ++j) {
                int t = sl * 4 + j - d;
                if (t >= 0 && t <= 8) dst[t] = (__bf16)vv[j];
            }
        }
        __syncthreads();
        #pragma unroll
        for (int it = 0; it < 9; ++it) {
            bf16x8 bf;
            #pragma unroll
            for (int j = 0; j < 4; ++j) { bf[j] = (__bf16)wr[2 * it][j]; bf[j + 4] = (__bf16)wr[2 * it + 1][j]; }
            const int kk0 = it * 32;
            #pragma unroll
            for (int bt = 0; bt < 4; ++bt) {
                bf16x8 af = *reinterpret_cast<const bf16x8*>(&Alds[bt * 16 + m16][kk0 + ko]);
                acc[bt] = __builtin_amdgcn_mfma_f32_16x16x32_bf16(af, bf, acc[bt], 0, 0, 0);
            }
        }
    }
    const float bv = bias[w * 64 + o];
    const int r0 = (lane >> 4) * 4;
    float* outp = out + (size_t)w * 64 + o;
    #pragma unroll
    for (int bt = 0; bt < 4; ++bt) {
        #pragma unroll
        for (int r = 0; r < 4; ++r) {
            int b = bt * 16 + r0 + r;
            outp[(size_t)b * 65536] = acc[bt][r] + bv;
        }
    }
}

extern "C" void kernel_launch(void* const* d_in, const int* in_sizes, int n_in,
                              void* d_out, int out_size, void* d_ws, size_t ws_size,
                              hipStream_t stream) {
    const float* x    = (const float*)d_in[0];
    const float* wts  = (const float*)d_in[1];
    const float* bias = (const float*)d_in[2];
    float* out = (float*)d_out;

    if (ws_size >= XT_BYTES) {
        __bf16* xt = (__bf16*)d_ws;
        xt_transpose_kernel<<<dim3(2056), dim3(256), 0, stream>>>(x, xt);
        lc1d_main_kernel<<<dim3(1024), dim3(256), 0, stream>>>(xt, wts, bias, out);
    } else {
        lc1d_fallback_kernel<<<dim3(1024), dim3(256), 0, stream>>>(x, wts, bias, out);
    }
}